// Round 2
// baseline (185.191 us; speedup 1.0000x reference)
//
#include <hip/hip_runtime.h>

// crossCorrelation3D: local (9x9x9) normalized cross-correlation loss, fused.
// B=2, C=1, D=H=W=160, fp32. Output = -mean(cc), scalar.
//
// Strategy: one fused kernel. Block = 16x16 (h,w) tile, marches DCHUNK=32
// depths. Per depth: compute HW-box-summed plane P[5][16][16] in LDS
// (separable: 24x24 halo load -> w 9-sums -> h sliding 9-sums). D-direction
// window kept per-thread in a register ring of 9 (statically indexed via
// unroll-by-9) with running sums S[5]. Epilogue: cc formula + block reduce +
// double atomicAdd into d_ws; tiny finalize kernel writes -mean.
//
// NOTE: reference transforms target t=(raw+1)/2 BEFORE zero-padded box sum,
// so padding must contribute t=0 (not 0.5). Transform is applied at load
// time for in-bounds voxels only.

constexpr int NB = 2;
constexpr int ND = 160;
constexpr int NH = 160;
constexpr int NW = 160;
constexpr int TH = 16;
constexpr int TW = 16;
constexpr int DCHUNK = 32;
constexpr int NDCH = ND / DCHUNK;            // 5
constexpr float INV_K = 1.0f / 729.0f;
constexpr double INV_COUNT = 1.0 / (double(NB) * ND * NH * NW); // 1/8192000

__device__ __forceinline__ void compute_plane(
    const float* __restrict__ in, const float* __restrict__ tg,
    int b, int dp, int h0, int w0, int tid,
    float* __restrict__ inT, float* __restrict__ tgT,
    float* __restrict__ tmp5, float* __restrict__ Pbuf)
{
    // ---- step 1: load 24x24 halo plane of input & target (float4 rows) ----
    // w0-4 is a multiple of 4, so rows are float4-aligned; each 4-wide segment
    // is entirely in-bounds or entirely out (w0 % 16 == 0, halo = 4).
    // Target is transformed t=(raw+1)/2 HERE so zero padding stays 0.
    if (tid < 144) {
        int r = tid / 6;
        int q = tid - r * 6;
        int gh = h0 - 4 + r;
        int gw = w0 - 4 + q * 4;
        float4 iv = make_float4(0.f, 0.f, 0.f, 0.f);
        float4 tv = make_float4(0.f, 0.f, 0.f, 0.f);
        if (((unsigned)gh < (unsigned)NH) && ((unsigned)gw < (unsigned)NW)) {
            long base = ((long)((b * ND + dp) * NH + gh)) * NW + gw;
            iv = *reinterpret_cast<const float4*>(in + base);
            float4 rv = *reinterpret_cast<const float4*>(tg + base);
            tv.x = fmaf(rv.x, 0.5f, 0.5f);
            tv.y = fmaf(rv.y, 0.5f, 0.5f);
            tv.z = fmaf(rv.z, 0.5f, 0.5f);
            tv.w = fmaf(rv.w, 0.5f, 0.5f);
        }
        reinterpret_cast<float4*>(inT)[r * 6 + q] = iv;
        reinterpret_cast<float4*>(tgT)[r * 6 + q] = tv;
    }
    __syncthreads();

    // ---- step 2: w-direction 9-sums of 5 product fields -> tmp5[5][24][16] ----
    {
        int pos = tid;
        #pragma unroll
        for (int rep = 0; rep < 2; ++rep) {
            if (pos < 384) {
                int r = pos >> 4, wo = pos & 15;
                const float* ir = inT + r * 24 + wo;
                const float* tr = tgT + r * 24 + wo;
                float s0 = 0.f, s1 = 0.f, s2 = 0.f, s3 = 0.f, s4 = 0.f;
                #pragma unroll
                for (int k = 0; k < 9; ++k) {
                    float ivv = ir[k];
                    float t = tr[k];            // already transformed (pad=0)
                    s0 += t;
                    s1 += ivv;
                    s2 = fmaf(t, t, s2);
                    s3 = fmaf(ivv, ivv, s3);
                    s4 = fmaf(ivv, t, s4);
                }
                int o = r * 16 + wo;
                tmp5[0 * 384 + o] = s0;
                tmp5[1 * 384 + o] = s1;
                tmp5[2 * 384 + o] = s2;
                tmp5[3 * 384 + o] = s3;
                tmp5[4 * 384 + o] = s4;
            }
            pos += 256;
        }
    }
    __syncthreads();

    // ---- step 3: h-direction sliding 9-sums -> Pbuf[5][16][16] ----
    if (tid < 80) {
        int f = tid >> 4, w = tid & 15;
        const float* basep = tmp5 + f * 384 + w;
        float s = 0.f;
        #pragma unroll
        for (int r = 0; r < 8; ++r) s += basep[r * 16];
        #pragma unroll
        for (int ho = 0; ho < 16; ++ho) {
            s += basep[(ho + 8) * 16];
            Pbuf[f * 256 + ho * 16 + w] = s;
            s -= basep[ho * 16];
        }
    }
    __syncthreads();
}

__global__ void __launch_bounds__(256)
cc3d_main(const float* __restrict__ in, const float* __restrict__ tg,
          const float* __restrict__ fl, double* __restrict__ acc_out)
{
    __shared__ float inT[24 * 24];
    __shared__ float tgT[24 * 24];
    __shared__ float tmp5[5 * 24 * 16];
    __shared__ float Pbuf[5 * 16 * 16];
    __shared__ float red[4];

    const int tid = threadIdx.x;
    const int w0 = blockIdx.x * TW;
    const int h0 = blockIdx.y * TH;
    const int bz = blockIdx.z;
    const int b  = bz / NDCH;
    const int d0 = (bz - b * NDCH) * DCHUNK;

    // D-direction ring of 9 plane values per field, statically indexed.
    float ring[45];
    #pragma unroll
    for (int i = 0; i < 45; ++i) ring[i] = 0.f;
    float S[5] = {0.f, 0.f, 0.f, 0.f, 0.f};
    float acc = 0.f;

    // ---- prefill planes d0-4 .. d0+3 into ring slots 0..7 ----
    #pragma unroll
    for (int l = 0; l < 8; ++l) {
        int dp = d0 - 4 + l;          // <= 131, only lower bound can fail
        bool valid = (dp >= 0);       // block-uniform
        if (valid) compute_plane(in, tg, b, dp, h0, w0, tid, inT, tgT, tmp5, Pbuf);
        #pragma unroll
        for (int f = 0; f < 5; ++f) {
            float pv = valid ? Pbuf[f * 256 + tid] : 0.f;
            ring[f * 9 + l] = pv;
            S[f] += pv;
        }
    }

    // ---- main march over outputs d0 .. d0+DCHUNK-1 ----
    for (int jbase = 0; jbase < DCHUNK; jbase += 9) {
        #pragma unroll
        for (int jj = 0; jj < 9; ++jj) {
            int j = jbase + jj;
            if (j < DCHUNK) {         // block-uniform guard
                int dout = d0 + j;
                int dp = dout + 4;
                bool valid = (dp < ND);  // block-uniform
                if (valid) compute_plane(in, tg, b, dp, h0, w0, tid, inT, tgT, tmp5, Pbuf);
                const int slot = (jj + 8) % 9;   // compile-time (jbase % 9 == 0)
                #pragma unroll
                for (int f = 0; f < 5; ++f) {
                    float pn = valid ? Pbuf[f * 256 + tid] : 0.f;
                    S[f] += pn - ring[f * 9 + slot];
                    ring[f * 9 + slot] = pn;
                }
                int hh = tid >> 4, ww = tid & 15;
                long fidx = ((long)((b * ND + dout) * NH + (h0 + hh))) * NW + (w0 + ww);
                float x = fl[fidx];
                float wgt = 1.0f / (1.0f + __expf(-x));   // sigmoid, GAMMA=1
                float Ts = S[0], Is = S[1], TTs = S[2], IIs = S[3], ITs = S[4];
                float Ihat = Is * INV_K;
                float That = Ts * INV_K;
                float cross = ITs - Ihat * Ts - That * Is + That * Ihat * 729.0f;
                float T_var = TTs - 2.0f * That * Ts + That * That * 729.0f;
                float I_var = IIs - 2.0f * Ihat * Is + Ihat * Ihat * 729.0f;
                float cc = cross * cross * wgt / (T_var * I_var + 1e-5f);
                acc += cc;
            }
        }
    }

    // ---- block reduction -> double atomic into workspace ----
    #pragma unroll
    for (int off = 32; off > 0; off >>= 1) acc += __shfl_down(acc, off);
    if ((tid & 63) == 0) red[tid >> 6] = acc;
    __syncthreads();
    if (tid == 0) {
        double v = (double)red[0] + (double)red[1] + (double)red[2] + (double)red[3];
        atomicAdd(acc_out, v);
    }
}

__global__ void cc3d_finalize(const double* __restrict__ acc, float* __restrict__ out)
{
    out[0] = (float)(-(acc[0] * INV_COUNT));
}

extern "C" void kernel_launch(void* const* d_in, const int* in_sizes, int n_in,
                              void* d_out, int out_size, void* d_ws, size_t ws_size,
                              hipStream_t stream)
{
    const float* in = (const float*)d_in[0];   // 'input'
    const float* tg = (const float*)d_in[1];   // 'target'
    const float* fl = (const float*)d_in[2];   // 'flow'
    float* out = (float*)d_out;
    double* acc = (double*)d_ws;

    hipMemsetAsync(d_ws, 0, sizeof(double), stream);  // graph-safe memset node

    dim3 grid(NW / TW, NH / TH, NB * NDCH);  // (10, 10, 10) = 1000 blocks
    cc3d_main<<<grid, dim3(256), 0, stream>>>(in, tg, fl, acc);
    cc3d_finalize<<<1, 1, 0, stream>>>(acc, out);
}